// Round 15
// baseline (995.383 us; speedup 1.0000x reference)
//
#include <hip/hip_runtime.h>
#include <hip/hip_cooperative_groups.h>
#include <math.h>

namespace cg = cooperative_groups;

// RipsLayer: dim-0 persistence of Rips filtration on 4096 points in R^64.
// R15: build_d + init + all Boruvka rounds fused into ONE cooperative
// kernel (256 blocks x 1024 thr, grid.sync between phases) — removes ~25
// kernel launches (~100us) and dead rounds. Cross-XCD discipline:
//   - D: plain writes + __threadfence() + grid.sync before any reader.
//   - best[]: device-scope atomics only (atomicMin / AGENT load+store),
//     3-buffer rotation (round r: min into r%3, reset (r+1)%3) -> one
//     grid sync per round suffices, no reset/read race.
//   - comp: LDS-only; EVERY block runs the deterministic merge locally
//     (races proven outcome-deterministic in R8), so comp never crosses
//     XCDs. Only block 0 emits edges.
// Replay = R13/R14's verified fully-parallel reconstruction, separate
// launch (kernel boundary flushes block0's edges to coherence).
// Fallback: R14 multi-kernel cached-D path if ws too small or coop
// launch fails (worst case = R14's 641us).

#define N 4096
#define DF 64
#define INF __builtin_huge_valf()

__device__ __forceinline__ unsigned long long aload64(const unsigned long long* p) {
    return __hip_atomic_load(p, __ATOMIC_RELAXED, __HIP_MEMORY_SCOPE_AGENT);
}
__device__ __forceinline__ void astore64(unsigned long long* p, unsigned long long v) {
    __hip_atomic_store(p, v, __ATOMIC_RELAXED, __HIP_MEMORY_SCOPE_AGENT);
}

// ---------------------------------------------------------------------------
// Standalone build_d (R0-verified) — fallback path only.
// ---------------------------------------------------------------------------
__global__ __launch_bounds__(256) void build_d_kernel(const float* __restrict__ x,
                                                      float* __restrict__ D) {
    __shared__ float As[64][68];
    __shared__ float Bs[64][68];
    const int bi = blockIdx.y * 64;
    const int bj = blockIdx.x * 64;
    const int t = threadIdx.x;

#pragma unroll
    for (int g = 0; g < 4; ++g) {
        int idx = t + 256 * g;
        int row = idx >> 4;
        int k4 = (idx & 15) << 2;
        *(float4*)(&As[row][k4]) = *(const float4*)(x + (size_t)(bi + row) * DF + k4);
        *(float4*)(&Bs[row][k4]) = *(const float4*)(x + (size_t)(bj + row) * DF + k4);
    }
    __syncthreads();

    const int ti = (t >> 4) << 2;
    const int tj = (t & 15) << 2;
    float acc[4][4];
#pragma unroll
    for (int r = 0; r < 4; ++r)
#pragma unroll
        for (int c = 0; c < 4; ++c) acc[r][c] = 0.0f;

    for (int k = 0; k < 64; k += 4) {
        float4 a[4], b[4];
#pragma unroll
        for (int r = 0; r < 4; ++r) a[r] = *(const float4*)(&As[ti + r][k]);
#pragma unroll
        for (int c = 0; c < 4; ++c) b[c] = *(const float4*)(&Bs[tj + c][k]);
#pragma unroll
        for (int r = 0; r < 4; ++r)
#pragma unroll
            for (int c = 0; c < 4; ++c) {
                float d0 = a[r].x - b[c].x;
                float d1 = a[r].y - b[c].y;
                float d2 = a[r].z - b[c].z;
                float d3 = a[r].w - b[c].w;
                float s = acc[r][c];
                s = fmaf(d0, d0, s);
                s = fmaf(d1, d1, s);
                s = fmaf(d2, d2, s);
                s = fmaf(d3, d3, s);
                acc[r][c] = s;
            }
    }
#pragma unroll
    for (int r = 0; r < 4; ++r) {
        int i = bi + ti + r;
        float4 v;
        float* vp = &v.x;
#pragma unroll
        for (int c = 0; c < 4; ++c) {
            int j = bj + tj + c;
            vp[c] = (i == j) ? INF : sqrtf(fmaxf(acc[r][c], 1e-12f));
        }
        *(float4*)(D + (size_t)i * N + (bj + tj)) = v;
    }
}

// ---------------------------------------------------------------------------
__global__ __launch_bounds__(256) void init_kernel(unsigned* comp,
                                                   unsigned long long* best,
                                                   unsigned* nedges, unsigned* done) {
    int i = blockIdx.x * 256 + threadIdx.x;
    if (i < N) {
        comp[i] = (unsigned)i;
        best[i] = ~0ULL;
    }
    if (i == 0) { *nedges = 0u; *done = 0u; }
}

// ---------------------------------------------------------------------------
// Fallback cached-D minedge (R14-verified).
// ---------------------------------------------------------------------------
__global__ __launch_bounds__(256) void minedge_d_kernel(const float* __restrict__ D,
                                                        const unsigned* __restrict__ comp,
                                                        unsigned long long* __restrict__ best,
                                                        const unsigned* __restrict__ done) {
    if (*done) return;
    __shared__ unsigned compc[N];
    __shared__ unsigned long long keybuf[256];
    const int t = threadIdx.x;
    const int b = blockIdx.x;
    const int r = t >> 4;
    const int j = t & 15;
    const int rowv = b * 16 + r;

    for (int v = t; v < N; v += 256) compc[v] = comp[v];
    __syncthreads();
    const unsigned cr = compc[rowv];
    const float4* rowp = (const float4*)(D + (size_t)rowv * N);
    unsigned long long mykey = ~0ULL;
#pragma unroll 4
    for (int k = 0; k < 64; ++k) {
        float4 v4 = rowp[j + 16 * k];
        int c0 = 4 * (j + 16 * k);
        const float* vp = &v4.x;
#pragma unroll
        for (int q = 0; q < 4; ++q) {
            int c = c0 + q;
            if (compc[c] != cr) {
                unsigned long long key =
                    ((unsigned long long)__float_as_uint(vp[q]) << 24) |
                    ((unsigned long long)(unsigned)rowv << 12) | (unsigned)c;
                mykey = key < mykey ? key : mykey;
            }
        }
    }
    keybuf[t] = mykey;
    __syncthreads();
    if (t < 16) {
        unsigned long long k = ~0ULL;
#pragma unroll
        for (int i = 0; i < 16; ++i) {
            unsigned long long v2 = keybuf[t * 16 + i];
            k = v2 < k ? v2 : k;
        }
        if (k != ~0ULL) atomicMin(&best[compc[b * 16 + t]], k);
    }
}

// ---------------------------------------------------------------------------
// Fallback merge (R14-verified; thread-count agnostic).
// ---------------------------------------------------------------------------
__global__ void merge_kernel(unsigned* comp, unsigned long long* best,
                             unsigned long long* edges, unsigned* nedges,
                             unsigned* done) {
    if (*done) return;
    __shared__ unsigned cl[N];
    __shared__ unsigned np[N];
    __shared__ unsigned cnt;
    const int t = threadIdx.x;
    const int bs = blockDim.x;
    for (int v = t; v < N; v += bs) cl[v] = comp[v];
    __syncthreads();
    for (int v = t; v < N; v += bs) {
        unsigned p;
        if (cl[v] == (unsigned)v) {
            unsigned long long k = best[v];
            p = (k != ~0ULL) ? cl[(unsigned)(k & 0xFFFu)] : (unsigned)v;
        } else {
            p = cl[v];
        }
        np[v] = p;
    }
    __syncthreads();
    for (int v = t; v < N; v += bs) {
        if (cl[v] == (unsigned)v) {
            unsigned p = np[v];
            if (p != (unsigned)v) {
                bool mutual = (np[p] == (unsigned)v);
                if (mutual && (unsigned)v < p) {
                    np[v] = (unsigned)v;
                } else {
                    unsigned idx = atomicAdd(nedges, 1u);
                    edges[idx] = best[v];
                }
            }
        }
    }
    __syncthreads();
    for (int it = 0; it < 12; ++it) {
        for (int v = t; v < N; v += bs) np[v] = np[np[v]];
        __syncthreads();
    }
    if (t == 0) cnt = 0;
    __syncthreads();
    unsigned local = 0;
    for (int v = t; v < N; v += bs) {
        comp[v] = np[v];
        best[v] = ~0ULL;
        if (np[v] == (unsigned)v) ++local;
    }
    atomicAdd(&cnt, local);
    __syncthreads();
    if (t == 0 && cnt == 1u) *done = 1u;
}

// ---------------------------------------------------------------------------
// Fused cooperative kernel: build D + init + all Boruvka rounds.
// 256 blocks x 1024 threads, ~152 KB LDS (1 block/CU -> coop-resident).
// ---------------------------------------------------------------------------
__global__ __launch_bounds__(1024) void fused_boruvka(
        const float* __restrict__ x, float* __restrict__ D,
        unsigned long long* best,   // [3][N], device-scope atomics only
        unsigned long long* edges,  // written by block 0 only
        unsigned* nedges) {
    __shared__ __align__(16) unsigned char lds[155648];
    __shared__ unsigned ne_cnt, cnt_sh, ne_base;
    unsigned* comp = (unsigned*)lds;  // [4096] u32, block-local, persistent
    const int t = threadIdx.x;
    const int b = blockIdx.x;
    cg::grid_group grid = cg::this_grid();

    // ---- phase 0: build 16 D-tiles (4 teams x 4 iters) + init ----
    {
        const int team = t >> 8, tt = t & 255;
        float(*As)[68] = (float(*)[68])(lds + 16384 + team * 17408);
        float(*Bs)[68] = (float(*)[68])(lds + 16384 + 69632 + team * 17408);
        for (int it = 0; it < 4; ++it) {
            const int tile = b * 16 + it * 4 + team;
            const int bi = (tile >> 6) * 64;
            const int bj = (tile & 63) * 64;
#pragma unroll
            for (int g = 0; g < 4; ++g) {
                int idx = tt + 256 * g;
                int row = idx >> 4, k4 = (idx & 15) << 2;
                *(float4*)(&As[row][k4]) =
                    *(const float4*)(x + (size_t)(bi + row) * DF + k4);
                *(float4*)(&Bs[row][k4]) =
                    *(const float4*)(x + (size_t)(bj + row) * DF + k4);
            }
            __syncthreads();
            const int ti = (tt >> 4) << 2, tj = (tt & 15) << 2;
            float acc[4][4];
#pragma unroll
            for (int r = 0; r < 4; ++r)
#pragma unroll
                for (int c = 0; c < 4; ++c) acc[r][c] = 0.0f;
            for (int k = 0; k < 64; k += 4) {
                float4 a[4], bb[4];
#pragma unroll
                for (int r = 0; r < 4; ++r) a[r] = *(const float4*)(&As[ti + r][k]);
#pragma unroll
                for (int c = 0; c < 4; ++c) bb[c] = *(const float4*)(&Bs[tj + c][k]);
#pragma unroll
                for (int r = 0; r < 4; ++r)
#pragma unroll
                    for (int c = 0; c < 4; ++c) {
                        float d0 = a[r].x - bb[c].x;
                        float d1 = a[r].y - bb[c].y;
                        float d2 = a[r].z - bb[c].z;
                        float d3 = a[r].w - bb[c].w;
                        float s = acc[r][c];
                        s = fmaf(d0, d0, s);
                        s = fmaf(d1, d1, s);
                        s = fmaf(d2, d2, s);
                        s = fmaf(d3, d3, s);
                        acc[r][c] = s;
                    }
            }
#pragma unroll
            for (int r = 0; r < 4; ++r) {
                int i = bi + ti + r;
                float4 v;
                float* vp = &v.x;
#pragma unroll
                for (int c = 0; c < 4; ++c) {
                    int j = bj + tj + c;
                    vp[c] = (i == j) ? INF : sqrtf(fmaxf(acc[r][c], 1e-12f));
                }
                *(float4*)(D + (size_t)i * N + (bj + tj)) = v;
            }
            __syncthreads();
        }
        for (int v = t; v < N; v += 1024) comp[v] = (unsigned)v;
        if (t < 16) {
            astore64(&best[(size_t)0 * N + b * 16 + t], ~0ULL);
            astore64(&best[(size_t)1 * N + b * 16 + t], ~0ULL);
            astore64(&best[(size_t)2 * N + b * 16 + t], ~0ULL);
        }
        if (t == 0) ne_base = 0u;
    }
    __threadfence();
    grid.sync();

    // ---- Boruvka rounds: 1 grid.sync per round (3-buffer rotation) ----
    for (int round = 0; round < 12; ++round) {
        const int cur = round % 3;
        const int nxt = (round + 1) % 3;
        // minedge: one wave per row, u64 shfl-min reduce
        {
            const int r = t >> 6, lane = t & 63;
            const int rowv = b * 16 + r;
            const unsigned cr = comp[rowv];
            const float4* rowp = (const float4*)(D + (size_t)rowv * N);
            unsigned long long mykey = ~0ULL;
#pragma unroll 4
            for (int k = 0; k < 16; ++k) {
                float4 v4 = rowp[lane + 64 * k];
                int c0 = 4 * (lane + 64 * k);
                const float* vp = &v4.x;
#pragma unroll
                for (int q = 0; q < 4; ++q) {
                    int c = c0 + q;
                    if (comp[c] != cr) {
                        unsigned long long key =
                            ((unsigned long long)__float_as_uint(vp[q]) << 24) |
                            ((unsigned long long)(unsigned)rowv << 12) | (unsigned)c;
                        mykey = key < mykey ? key : mykey;
                    }
                }
            }
#pragma unroll
            for (int off = 32; off > 0; off >>= 1) {
                unsigned long long o = __shfl_down(mykey, (unsigned)off, 64);
                mykey = o < mykey ? o : mykey;
            }
            if (lane == 0 && mykey != ~0ULL)
                atomicMin(&best[(size_t)cur * N + cr], mykey);
            // reset the buffer that round+1 will min into (nobody reads it
            // in the concurrent window: merge r reads cur, laggard merge
            // r-1 read (r+2)%3 which != nxt)
            if (t < 16) astore64(&best[(size_t)nxt * N + b * 16 + t], ~0ULL);
        }
        __threadfence();
        grid.sync();

        // merge: every block computes identical result on its LDS comp
        bool done;
        {
            unsigned* np = (unsigned*)(lds + 16384);
            unsigned long long kreg[4];
#pragma unroll
            for (int i = 0; i < 4; ++i) {
                int v = t + 1024 * i;
                unsigned p;
                unsigned long long k = ~0ULL;
                if (comp[v] == (unsigned)v) {
                    k = aload64(&best[(size_t)cur * N + v]);
                    p = (k != ~0ULL) ? comp[(unsigned)(k & 0xFFFu)] : (unsigned)v;
                } else {
                    p = comp[v];
                }
                np[v] = p;
                kreg[i] = k;
            }
            if (t == 0) ne_cnt = 0u;
            __syncthreads();
#pragma unroll
            for (int i = 0; i < 4; ++i) {
                int v = t + 1024 * i;
                if (comp[v] == (unsigned)v) {
                    unsigned p = np[v];
                    if (p != (unsigned)v) {
                        bool mutual = (np[p] == (unsigned)v);
                        if (mutual && (unsigned)v < p) {
                            np[v] = (unsigned)v;
                        } else {
                            unsigned idx = atomicAdd(&ne_cnt, 1u);
                            if (b == 0) edges[ne_base + idx] = kreg[i];
                        }
                    }
                }
            }
            __syncthreads();
            for (int it = 0; it < 12; ++it) {
#pragma unroll
                for (int i = 0; i < 4; ++i) {
                    int v = t + 1024 * i;
                    np[v] = np[np[v]];  // monotone; benign race (R8-verified)
                }
                __syncthreads();
            }
            if (t == 0) cnt_sh = 0u;
            __syncthreads();
            unsigned local = 0;
#pragma unroll
            for (int i = 0; i < 4; ++i) {
                int v = t + 1024 * i;
                unsigned r2 = np[v];
                comp[v] = r2;
                if (r2 == (unsigned)v) ++local;
            }
            atomicAdd(&cnt_sh, local);
            __syncthreads();
            if (t == 0) ne_base += ne_cnt;
            done = (cnt_sh == 1u);
            __syncthreads();  // protect np region + ne_base for next round
        }
        if (done) break;  // uniform across blocks (deterministic merge)
    }
    if (b == 0 && t == 0) *nedges = ne_base;
}

// ---------------------------------------------------------------------------
// Replay (R13/R14-verified): CSR + BFS -> ANSV -> S -> r-major sort ->
// segmented scan -> pointer-doubling -> scatter. 1024 threads, 1 block.
// ---------------------------------------------------------------------------
__global__ __launch_bounds__(1024) void replay_kernel(
        const unsigned long long* __restrict__ edges,
        const unsigned* __restrict__ nedges, float* __restrict__ out) {
    __shared__ __align__(16) unsigned char pool[156680];
    __shared__ unsigned chg;
    unsigned* off = (unsigned*)(pool + 65536);
    unsigned long long* ent = (unsigned long long*)(pool + 0);
    unsigned short* par = (unsigned short*)(pool + 81928);
    unsigned* keyw = (unsigned*)(pool + 90120);
    unsigned long long* key64 = (unsigned long long*)(pool + 0);
    unsigned long long* order = (unsigned long long*)(pool + 0);
    unsigned* ptr = (unsigned*)(pool + 106504);
    unsigned* Sa = (unsigned*)(pool + 32768);
    unsigned* Sb = (unsigned*)(pool + 49152);
    unsigned* T = (unsigned*)(pool + 65536);
    unsigned* vA = (unsigned*)(pool + 122888);
    unsigned* jA = (unsigned*)(pool + 139272);
    unsigned* vB = (unsigned*)(pool + 0);
    unsigned* jB = (unsigned*)(pool + 16384);
    unsigned* csum = (unsigned*)(pool + 155656);
    const int t = threadIdx.x;
    const unsigned ne = *nedges;

    for (int v = t; v < N; v += 1024) off[v] = 0u;
    if (t == 0) off[N] = 0u;
    for (int k = t; k < N - 1; k += 1024) out[2 * k] = 0.0f;
    __syncthreads();
    for (int e = t; e < (int)ne; e += 1024) {
        unsigned long long k = edges[e];
        atomicAdd(&off[(unsigned)(k >> 12) & 0xFFFu], 1u);
        atomicAdd(&off[(unsigned)k & 0xFFFu], 1u);
    }
    __syncthreads();
    unsigned sloc = 0;
    unsigned loc[16];
    if (t < 256) {
        int base = t * 16;
#pragma unroll
        for (int i = 0; i < 16; ++i) {
            unsigned d = off[base + i];
            loc[i] = sloc;
            sloc += d;
        }
        csum[t] = sloc;
    }
    __syncthreads();
    for (int d = 1; d < 256; d <<= 1) {
        unsigned addv = 0;
        if (t < 256 && t >= d) addv = csum[t - d];
        __syncthreads();
        if (t < 256) csum[t] += addv;
        __syncthreads();
    }
    if (t < 256) {
        int base = t * 16;
        unsigned excl = csum[t] - sloc;
#pragma unroll
        for (int i = 0; i < 16; ++i) {
            unsigned o = loc[i] + excl;
            off[base + i] = o;
            keyw[base + i] = o;
        }
        if (t == 255) off[N] = csum[255];
    }
    __syncthreads();
    for (int e = t; e < (int)ne; e += 1024) {
        unsigned long long k = edges[e];
        unsigned a = (unsigned)(k >> 12) & 0xFFFu;
        unsigned b = (unsigned)k & 0xFFFu;
        unsigned long long wb = k >> 24;
        unsigned p1 = atomicAdd(&keyw[a], 1u);
        ent[p1] = (wb << 12) | b;
        unsigned p2 = atomicAdd(&keyw[b], 1u);
        ent[p2] = (wb << 12) | a;
    }
    __syncthreads();
    for (int v = t; v < N; v += 1024) keyw[v] = 0xFFFFFFFFu;
    __syncthreads();
    if (t == 0) {
        keyw[0] = 0u;
        par[0] = 0;
        chg = 0u;
    }
    __syncthreads();
    for (;;) {
        for (int v = t; v < N; v += 1024) {
            if (keyw[v] == 0xFFFFFFFFu) {
                unsigned o = off[v], oe = off[v + 1];
                for (unsigned e = o; e < oe; ++e) {
                    unsigned long long en = ent[e];
                    unsigned nb = (unsigned)en & 0xFFFu;
                    if (keyw[nb] != 0xFFFFFFFFu) {
                        par[v] = (unsigned short)nb;
                        keyw[v] = (unsigned)(en >> 12);
                        chg = 1u;
                        break;
                    }
                }
            }
        }
        __syncthreads();
        unsigned fin = (chg == 0u);
        __syncthreads();
        if (t == 0) chg = 0u;
        __syncthreads();
        if (fin) break;
    }
    for (int v = t; v < N; v += 1024) {
        key64[v] = (v == 0) ? ~0ULL
                            : (((unsigned long long)keyw[v]) << 24) |
                                  ((unsigned long long)par[v] << 12) | (unsigned)v;
        ptr[v] = (v == 0) ? 0u : (unsigned)par[v];
    }
    __syncthreads();
    for (;;) {
        for (int v = t; v < N; v += 1024) {
            unsigned p = ptr[v];
            if (key64[p] <= key64[v]) {
                unsigned q = ptr[p];
                if (q != p) {
                    ptr[v] = q;
                    chg = 1u;
                }
            }
        }
        __syncthreads();
        unsigned fin = (chg == 0u);
        __syncthreads();
        if (t == 0) chg = 0u;
        __syncthreads();
        if (fin) break;
    }
    unsigned* Sc = Sa;
    unsigned* Sn = Sb;
    for (int v = t; v < N; v += 1024) Sc[v] = 1u;
    __syncthreads();
    for (int round = 0; round < 64; ++round) {
        for (int v = t; v < N; v += 1024) Sn[v] = 1u;
        __syncthreads();
        for (int v = t; v < N; v += 1024)
            if (v != 0) atomicAdd(&Sn[ptr[v]], Sc[v]);
        __syncthreads();
        for (int v = t; v < N; v += 1024)
            if (Sn[v] != Sc[v]) chg = 1u;
        __syncthreads();
        unsigned fin = (chg == 0u);
        __syncthreads();
        if (t == 0) chg = 0u;
        __syncthreads();
        unsigned* tmp = Sc; Sc = Sn; Sn = tmp;
        if (fin) break;
    }
    for (int v = t; v < N; v += 1024) {
        order[v] = (v == 0)
                       ? (0xFFFFFull << 44)
                       : (((unsigned long long)ptr[v]) << 44) |
                             (((unsigned long long)keyw[v]) << 12) | (unsigned)v;
    }
    __syncthreads();
    for (unsigned k = 2; k <= 4096; k <<= 1) {
        for (unsigned j = k >> 1; j > 0; j >>= 1) {
            for (unsigned i = t; i < 4096; i += 1024) {
                unsigned p = i ^ j;
                if (p > i) {
                    unsigned long long a = order[i], b = order[p];
                    bool up = ((i & k) == 0);
                    if ((a > b) == up) {
                        order[i] = b;
                        order[p] = a;
                    }
                }
            }
            __syncthreads();
        }
    }
    for (int i = t; i < 4096; i += 1024) {
        unsigned vv = (unsigned)order[i] & 0xFFFu;
        T[i] = Sc[vv];
    }
    __syncthreads();
    for (int d = 1; d < 4096; d <<= 1) {
        unsigned addv[4];
#pragma unroll
        for (int q = 0; q < 4; ++q) {
            int i = t + 1024 * q;
            addv[q] = 0;
            if (i >= d && (order[i] >> 44) == (order[i - d] >> 44)) addv[q] = T[i - d];
        }
        __syncthreads();
#pragma unroll
        for (int q = 0; q < 4; ++q) T[t + 1024 * q] += addv[q];
        __syncthreads();
    }
    for (int i = t; i < 4096; i += 1024) {
        unsigned vv = (unsigned)order[i] & 0xFFFu;
        if (vv) {
            vA[vv] = 1u + T[i] - Sc[vv];
            jA[vv] = ptr[vv];
        }
    }
    if (t == 0) {
        vA[0] = 0u;
        jA[0] = 0u;
    }
    __syncthreads();
    {
        unsigned *va = vA, *vb = vB, *ja = jA, *jb = jB;
        for (int r = 0; r < 12; ++r) {
            for (int v = t; v < N; v += 1024) {
                unsigned j2 = ja[v];
                vb[v] = va[v] + va[j2];
                jb[v] = ja[j2];
            }
            __syncthreads();
            unsigned* tmp;
            tmp = va; va = vb; vb = tmp;
            tmp = ja; ja = jb; jb = tmp;
        }
        for (int v = t; v < N; v += 1024) {
            if (v) out[2 * (va[v] - 1) + 1] = __uint_as_float(keyw[v]);
        }
    }
}

// ---------------------------------------------------------------------------
extern "C" void kernel_launch(void* const* d_in, const int* in_sizes, int n_in,
                              void* d_out, int out_size, void* d_ws, size_t ws_size,
                              hipStream_t stream) {
    const float* x = (const float*)d_in[0];
    float* out = (float*)d_out;  // [N-1][2]: (birth=0, death)
    const size_t dbytes = (size_t)N * N * 4;

    if (ws_size >= dbytes + 135168) {
        // Cooperative fused path.
        float* D = (float*)d_ws;
        unsigned char* st = (unsigned char*)d_ws + dbytes;
        unsigned long long* best = (unsigned long long*)st;             // 3*32768
        unsigned long long* edges = (unsigned long long*)(st + 98304); // 32760
        unsigned* nedges = (unsigned*)(st + 131072);

        void* args[5];
        args[0] = (void*)&x;
        args[1] = (void*)&D;
        args[2] = (void*)&best;
        args[3] = (void*)&edges;
        args[4] = (void*)&nedges;
        hipError_t e = hipLaunchCooperativeKernel((const void*)fused_boruvka,
                                                  dim3(256), dim3(1024), args, 0,
                                                  stream);
        if (e == hipSuccess) {
            replay_kernel<<<1, 1024, 0, stream>>>(edges, nedges, out);
            return;
        }
        // else fall through to multi-kernel path
    }
    // R14 multi-kernel cached-D fallback (verified, 641us).
    {
        float* D = (float*)d_ws;
        unsigned char* st = (unsigned char*)d_ws + dbytes;
        unsigned long long* best = (unsigned long long*)st;            // 32 KB
        unsigned* comp = (unsigned*)(st + 32768);                      // 16 KB
        unsigned long long* edges = (unsigned long long*)(st + 49152); // 32760 B
        unsigned* nedges = (unsigned*)(st + 81912);
        unsigned* done = (unsigned*)(st + 81916);

        dim3 grid(N / 64, N / 64);
        build_d_kernel<<<grid, 256, 0, stream>>>(x, D);
        init_kernel<<<16, 256, 0, stream>>>(comp, best, nedges, done);
        for (int r = 0; r < 12; ++r) {
            minedge_d_kernel<<<256, 256, 0, stream>>>(D, comp, best, done);
            merge_kernel<<<1, 1024, 0, stream>>>(comp, best, edges, nedges, done);
        }
        replay_kernel<<<1, 1024, 0, stream>>>(edges, nedges, out);
    }
}

// Round 16
// 491.471 us; speedup vs baseline: 2.0253x; 2.0253x over previous
//
#include <hip/hip_runtime.h>
#include <math.h>

// RipsLayer: dim-0 persistence of Rips filtration on 4096 points in R^64.
// R16: revert R15's cooperative fusion (grid.sync + dup merge + L2-defeat
// cost 1.8x vs separate kernels). R14 multi-kernel structure (verified
// 641us) + two cuts:
//  (1) build_d also emits round-0 Boruvka best (singleton comps -> per-row
//      min, 16-lane shfl_xor u64 reduce + atomicMin) -> round-0 minedge
//      (coldest full-D scan) eliminated.
//  (2) replay: BFS rooting (depth-bound, ~depth x 1.5us) replaced by
//      Euler-tour list-ranking (depth-independent, 14 Wyllie rounds):
//      twin[] recorded at CSR fill; next(s) = circular successor of
//      twin(s); cut before slot off[0]; in-place Wyllie with read/write
//      phase barriers; down-edge iff rank[s] > rank[twin[s]] -> par/keyw.
// Everything else verbatim from R14 (verified): cached-D minedge rounds,
// merge, ANSV -> S -> r-major sort -> segscan -> doubling -> scatter.

#define N 4096
#define DF 64
#define INF __builtin_huge_valf()

// ---------------------------------------------------------------------------
// build_d + round-0 best: D[i][j] = sqrt(max(|xi-xj|^2,1e-12)), diag=+inf;
// per-row min key atomicMin'd into best[row] (round-0 comps are singletons).
// ---------------------------------------------------------------------------
__global__ __launch_bounds__(256) void build_d_kernel(const float* __restrict__ x,
                                                      float* __restrict__ D,
                                                      unsigned long long* __restrict__ best) {
    __shared__ float As[64][68];
    __shared__ float Bs[64][68];
    const int bi = blockIdx.y * 64;
    const int bj = blockIdx.x * 64;
    const int t = threadIdx.x;

#pragma unroll
    for (int g = 0; g < 4; ++g) {
        int idx = t + 256 * g;
        int row = idx >> 4;
        int k4 = (idx & 15) << 2;
        *(float4*)(&As[row][k4]) = *(const float4*)(x + (size_t)(bi + row) * DF + k4);
        *(float4*)(&Bs[row][k4]) = *(const float4*)(x + (size_t)(bj + row) * DF + k4);
    }
    __syncthreads();

    const int ti = (t >> 4) << 2;
    const int tj = (t & 15) << 2;
    float acc[4][4];
#pragma unroll
    for (int r = 0; r < 4; ++r)
#pragma unroll
        for (int c = 0; c < 4; ++c) acc[r][c] = 0.0f;

    for (int k = 0; k < 64; k += 4) {
        float4 a[4], b[4];
#pragma unroll
        for (int r = 0; r < 4; ++r) a[r] = *(const float4*)(&As[ti + r][k]);
#pragma unroll
        for (int c = 0; c < 4; ++c) b[c] = *(const float4*)(&Bs[tj + c][k]);
#pragma unroll
        for (int r = 0; r < 4; ++r)
#pragma unroll
            for (int c = 0; c < 4; ++c) {
                float d0 = a[r].x - b[c].x;
                float d1 = a[r].y - b[c].y;
                float d2 = a[r].z - b[c].z;
                float d3 = a[r].w - b[c].w;
                float s = acc[r][c];
                s = fmaf(d0, d0, s);
                s = fmaf(d1, d1, s);
                s = fmaf(d2, d2, s);
                s = fmaf(d3, d3, s);
                acc[r][c] = s;
            }
    }
#pragma unroll
    for (int r = 0; r < 4; ++r) {
        int i = bi + ti + r;
        float4 v;
        float* vp = &v.x;
        unsigned long long mk = ~0ULL;
#pragma unroll
        for (int c = 0; c < 4; ++c) {
            int j = bj + tj + c;
            vp[c] = (i == j) ? INF : sqrtf(fmaxf(acc[r][c], 1e-12f));
            unsigned long long key =
                ((unsigned long long)__float_as_uint(vp[c]) << 24) |
                ((unsigned long long)(unsigned)i << 12) | (unsigned)j;
            mk = key < mk ? key : mk;
        }
        *(float4*)(D + (size_t)i * N + (bj + tj)) = v;
        // 16-lane row-group reduce (lanes share t>>4; xor 1/2/4/8 stays in group)
#pragma unroll
        for (int m = 1; m < 16; m <<= 1) {
            unsigned long long o = __shfl_xor(mk, m, 64);
            mk = o < mk ? o : mk;
        }
        if ((t & 15) == 0) atomicMin(&best[i], mk);
    }
}

// ---------------------------------------------------------------------------
__global__ __launch_bounds__(256) void init_kernel(unsigned* comp,
                                                   unsigned long long* best,
                                                   unsigned* nedges, unsigned* done) {
    int i = blockIdx.x * 256 + threadIdx.x;
    if (i < N) {
        comp[i] = (unsigned)i;
        best[i] = ~0ULL;
    }
    if (i == 0) { *nedges = 0u; *done = 0u; }
}

// ---------------------------------------------------------------------------
// Cached-D minedge (R14-verified).
// ---------------------------------------------------------------------------
__global__ __launch_bounds__(256) void minedge_d_kernel(const float* __restrict__ D,
                                                        const unsigned* __restrict__ comp,
                                                        unsigned long long* __restrict__ best,
                                                        const unsigned* __restrict__ done) {
    if (*done) return;
    __shared__ unsigned compc[N];
    __shared__ unsigned long long keybuf[256];
    const int t = threadIdx.x;
    const int b = blockIdx.x;
    const int r = t >> 4;
    const int j = t & 15;
    const int rowv = b * 16 + r;

    for (int v = t; v < N; v += 256) compc[v] = comp[v];
    __syncthreads();
    const unsigned cr = compc[rowv];
    const float4* rowp = (const float4*)(D + (size_t)rowv * N);
    unsigned long long mykey = ~0ULL;
#pragma unroll 4
    for (int k = 0; k < 64; ++k) {
        float4 v4 = rowp[j + 16 * k];
        int c0 = 4 * (j + 16 * k);
        const float* vp = &v4.x;
#pragma unroll
        for (int q = 0; q < 4; ++q) {
            int c = c0 + q;
            if (compc[c] != cr) {
                unsigned long long key =
                    ((unsigned long long)__float_as_uint(vp[q]) << 24) |
                    ((unsigned long long)(unsigned)rowv << 12) | (unsigned)c;
                mykey = key < mykey ? key : mykey;
            }
        }
    }
    keybuf[t] = mykey;
    __syncthreads();
    if (t < 16) {
        unsigned long long k = ~0ULL;
#pragma unroll
        for (int i = 0; i < 16; ++i) {
            unsigned long long v2 = keybuf[t * 16 + i];
            k = v2 < k ? v2 : k;
        }
        if (k != ~0ULL) atomicMin(&best[compc[b * 16 + t]], k);
    }
}

// ---------------------------------------------------------------------------
// Recompute minedge (fallback path when ws too small; R13-verified).
// ---------------------------------------------------------------------------
__global__ __launch_bounds__(256) void minedge_kernel(const float* __restrict__ x,
                                                      const unsigned* __restrict__ comp,
                                                      unsigned long long* __restrict__ best,
                                                      const unsigned* __restrict__ done) {
    if (*done) return;
    __shared__ float xr[16][64];
    __shared__ float xc[64][68];
    __shared__ unsigned compr[16];
    __shared__ unsigned compc[64];
    __shared__ unsigned long long keybuf[256];
    const int t = threadIdx.x;
    const int b = blockIdx.x;
    const int r = t >> 4;
    const int rowv = b * 16 + r;

    {
        int row = t >> 4, f4 = t & 15;
        *(float4*)&xr[row][f4 * 4] =
            *(const float4*)(x + (size_t)(b * 16 + row) * DF + f4 * 4);
        if (t < 16) compr[t] = comp[b * 16 + t];
    }
    __syncthreads();
    const unsigned cr = compr[r];
    unsigned long long mykey = ~0ULL;

    for (int tile = 0; tile < 64; ++tile) {
        {
#pragma unroll
            for (int q = 0; q < 4; ++q) {
                int idx = t + 256 * q;
                int col = idx >> 4, k4 = (idx & 15) * 4;
                *(float4*)&xc[col][k4] =
                    *(const float4*)(x + (size_t)(tile * 64 + col) * DF + k4);
            }
            if (t < 64) compc[t] = comp[tile * 64 + t];
        }
        __syncthreads();
#pragma unroll
        for (int q = 0; q < 4; ++q) {
            int c = (t & 15) + 16 * q;
            unsigned cc = compc[c];
            if (cc != cr) {
                float s = 0.0f;
#pragma unroll
                for (int k = 0; k < 64; k += 4) {
                    float4 a = *(const float4*)&xr[r][k];
                    float4 bb = *(const float4*)&xc[c][k];
                    float d0 = a.x - bb.x;
                    float d1 = a.y - bb.y;
                    float d2 = a.z - bb.z;
                    float d3 = a.w - bb.w;
                    s = fmaf(d0, d0, s);
                    s = fmaf(d1, d1, s);
                    s = fmaf(d2, d2, s);
                    s = fmaf(d3, d3, s);
                }
                float w = sqrtf(fmaxf(s, 1e-12f));
                unsigned long long key =
                    ((unsigned long long)__float_as_uint(w) << 24) |
                    ((unsigned long long)(unsigned)rowv << 12) |
                    (unsigned)(tile * 64 + c);
                mykey = key < mykey ? key : mykey;
            }
        }
        __syncthreads();
    }
    keybuf[t] = mykey;
    __syncthreads();
    if (t < 16) {
        unsigned long long k = ~0ULL;
#pragma unroll
        for (int i = 0; i < 16; ++i) {
            unsigned long long v2 = keybuf[t * 16 + i];
            k = v2 < k ? v2 : k;
        }
        if (k != ~0ULL) atomicMin(&best[compr[t]], k);
    }
}

// ---------------------------------------------------------------------------
// Boruvka merge (R14-verified; thread-count agnostic, launched with 1024).
// ---------------------------------------------------------------------------
__global__ void merge_kernel(unsigned* comp, unsigned long long* best,
                             unsigned long long* edges, unsigned* nedges,
                             unsigned* done) {
    if (*done) return;
    __shared__ unsigned cl[N];
    __shared__ unsigned np[N];
    __shared__ unsigned cnt;
    const int t = threadIdx.x;
    const int bs = blockDim.x;
    for (int v = t; v < N; v += bs) cl[v] = comp[v];
    __syncthreads();
    for (int v = t; v < N; v += bs) {
        unsigned p;
        if (cl[v] == (unsigned)v) {
            unsigned long long k = best[v];
            p = (k != ~0ULL) ? cl[(unsigned)(k & 0xFFFu)] : (unsigned)v;
        } else {
            p = cl[v];
        }
        np[v] = p;
    }
    __syncthreads();
    for (int v = t; v < N; v += bs) {
        if (cl[v] == (unsigned)v) {
            unsigned p = np[v];
            if (p != (unsigned)v) {
                bool mutual = (np[p] == (unsigned)v);
                if (mutual && (unsigned)v < p) {
                    np[v] = (unsigned)v;
                } else {
                    unsigned idx = atomicAdd(nedges, 1u);
                    edges[idx] = best[v];
                }
            }
        }
    }
    __syncthreads();
    for (int it = 0; it < 12; ++it) {
        for (int v = t; v < N; v += bs) np[v] = np[np[v]];
        __syncthreads();
    }
    if (t == 0) cnt = 0;
    __syncthreads();
    unsigned local = 0;
    for (int v = t; v < N; v += bs) {
        comp[v] = np[v];
        best[v] = ~0ULL;
        if (np[v] == (unsigned)v) ++local;
    }
    atomicAdd(&cnt, local);
    __syncthreads();
    if (t == 0 && cnt == 1u) *done = 1u;
}

// ---------------------------------------------------------------------------
// Replay: CSR(+twin) -> Euler-tour list-ranking rooting -> ANSV -> S ->
// r-major sort -> segmented scan -> pointer-doubling -> scatter.
// ---------------------------------------------------------------------------
__global__ __launch_bounds__(1024) void replay_kernel(
        const unsigned long long* __restrict__ edges,
        const unsigned* __restrict__ nedges, float* __restrict__ out) {
    __shared__ __align__(16) unsigned char pool[156680];
    __shared__ unsigned chg;
    // Overlays (live ranges disjoint):
    //  [0,65520)       ent u64[8190]      (live through rooting; then dead)
    //    [0,32768)       key64/order u64  (ANSV / sort, after rooting)
    //    [0,16384)       vB u32           (doubling)
    //    [16384,32768)   jB u32           (doubling)
    //    [32768,49152)   Sa u32           (S iter, after rooting)
    //    [49152,65536)   Sb u32
    //  [65536,81924)   off u32[4097]      (dead after rooting) / T (segscan)
    //  [81928,90120)   par u16[4096]
    //  [90120,106504)  keyw u32[4096]     (ins-ptrs, then wbits; live to end)
    //  [106504,122888) rank u16[8192] (rooting) / ptr u32[4096] (ANSV on)
    //  [122888,139272) nxt u16[8192] (rooting) / vA u32[4096]
    //  [139272,155656) twin u16[8192] (CSR fill->rooting) / jA u32[4096]
    //  [155656,156680) csum u32[256]
    unsigned* off = (unsigned*)(pool + 65536);
    unsigned long long* ent = (unsigned long long*)(pool + 0);
    unsigned short* par = (unsigned short*)(pool + 81928);
    unsigned* keyw = (unsigned*)(pool + 90120);
    unsigned long long* key64 = (unsigned long long*)(pool + 0);
    unsigned long long* order = (unsigned long long*)(pool + 0);
    unsigned* ptr = (unsigned*)(pool + 106504);
    unsigned short* rankA = (unsigned short*)(pool + 106504);
    unsigned short* nxtA = (unsigned short*)(pool + 122888);
    unsigned short* twin = (unsigned short*)(pool + 139272);
    unsigned* Sa = (unsigned*)(pool + 32768);
    unsigned* Sb = (unsigned*)(pool + 49152);
    unsigned* T = (unsigned*)(pool + 65536);
    unsigned* vA = (unsigned*)(pool + 122888);
    unsigned* jA = (unsigned*)(pool + 139272);
    unsigned* vB = (unsigned*)(pool + 0);
    unsigned* jB = (unsigned*)(pool + 16384);
    unsigned* csum = (unsigned*)(pool + 155656);
    const int t = threadIdx.x;
    const unsigned ne = *nedges;
    const int ns = 2 * (int)ne;  // directed slots

    // ---- CSR counts ----
    for (int v = t; v < N; v += 1024) off[v] = 0u;
    if (t == 0) off[N] = 0u;
    for (int k = t; k < N - 1; k += 1024) out[2 * k] = 0.0f;  // births
    __syncthreads();
    for (int e = t; e < (int)ne; e += 1024) {
        unsigned long long k = edges[e];
        atomicAdd(&off[(unsigned)(k >> 12) & 0xFFFu], 1u);
        atomicAdd(&off[(unsigned)k & 0xFFFu], 1u);
    }
    __syncthreads();
    // ---- exclusive prefix sum; keyw doubles as insertion pointers ----
    unsigned sloc = 0;
    unsigned loc[16];
    if (t < 256) {
        int base = t * 16;
#pragma unroll
        for (int i = 0; i < 16; ++i) {
            unsigned d = off[base + i];
            loc[i] = sloc;
            sloc += d;
        }
        csum[t] = sloc;
    }
    __syncthreads();
    for (int d = 1; d < 256; d <<= 1) {
        unsigned addv = 0;
        if (t < 256 && t >= d) addv = csum[t - d];
        __syncthreads();
        if (t < 256) csum[t] += addv;
        __syncthreads();
    }
    if (t < 256) {
        int base = t * 16;
        unsigned excl = csum[t] - sloc;
#pragma unroll
        for (int i = 0; i < 16; ++i) {
            unsigned o = loc[i] + excl;
            off[base + i] = o;
            keyw[base + i] = o;
        }
        if (t == 255) off[N] = csum[255];
    }
    __syncthreads();
    // ---- fill CSR: ent = (wbits<<12)|nbr ; record twins ----
    for (int e = t; e < (int)ne; e += 1024) {
        unsigned long long k = edges[e];
        unsigned a = (unsigned)(k >> 12) & 0xFFFu;
        unsigned b = (unsigned)k & 0xFFFu;
        unsigned long long wb = k >> 24;
        unsigned p1 = atomicAdd(&keyw[a], 1u);
        unsigned p2 = atomicAdd(&keyw[b], 1u);
        ent[p1] = (wb << 12) | b;
        ent[p2] = (wb << 12) | a;
        twin[p1] = (unsigned short)p2;
        twin[p2] = (unsigned short)p1;
    }
    __syncthreads();
    // ---- Euler tour rooting: next(s) = circular succ of twin(s) ----
    const unsigned s0 = off[0];  // first directed edge out of root 0
    for (int s = t; s < ns; s += 1024) {
        unsigned v = (unsigned)ent[s] & 0xFFFu;
        unsigned t2 = twin[s];
        unsigned nx = t2 + 1u;
        if (nx == off[v + 1]) nx = off[v];
        if (nx == s0) nx = 0xFFFFu;  // cut the cycle before s0
        nxtA[s] = (unsigned short)nx;
        rankA[s] = 1;
    }
    __syncthreads();
    // Wyllie list ranking, in-place with read-phase/write-phase barriers.
    for (int round = 0; round < 14; ++round) {
        unsigned short rr[8], nn[8];
#pragma unroll
        for (int q = 0; q < 8; ++q) {
            int s = t + 1024 * q;
            rr[q] = 0;
            nn[q] = 0xFFFFu;
            if (s < ns) {
                unsigned n2 = nxtA[s];
                if (n2 != 0xFFFFu) {
                    rr[q] = rankA[n2];
                    nn[q] = nxtA[n2];
                } else {
                    nn[q] = 0xFFFFu;
                }
            }
        }
        __syncthreads();
#pragma unroll
        for (int q = 0; q < 8; ++q) {
            int s = t + 1024 * q;
            if (s < ns) {
                if (nxtA[s] != 0xFFFFu) {
                    rankA[s] = (unsigned short)(rankA[s] + rr[q]);
                    nxtA[s] = nn[q];
                }
            }
        }
        __syncthreads();
    }
    // rank = 1-based distance to tour end; earlier edge => larger rank.
    // Down-edge (u->v): first traversal => rank[s] > rank[twin[s]].
    for (int s = t; s < ns; s += 1024) {
        unsigned t2 = twin[s];
        if (rankA[s] > rankA[t2]) {
            unsigned v = (unsigned)ent[s] & 0xFFFu;
            par[v] = (unsigned short)((unsigned)ent[t2] & 0xFFFu);
            keyw[v] = (unsigned)(ent[s] >> 12);
        }
    }
    if (t == 0) {
        par[0] = 0;
        chg = 0u;
    }
    __syncthreads();
    // ---- ANSV: key64 fill (ent dead; rank/nxt/twin dead) ----
    for (int v = t; v < N; v += 1024) {
        key64[v] = (v == 0) ? ~0ULL
                            : (((unsigned long long)keyw[v]) << 24) |
                                  ((unsigned long long)par[v] << 12) | (unsigned)v;
    }
    __syncthreads();  // key64 (overlays ent) ready before ptr init reads par
    for (int v = t; v < N; v += 1024) ptr[v] = (v == 0) ? 0u : (unsigned)par[v];
    __syncthreads();
    for (;;) {
        for (int v = t; v < N; v += 1024) {
            unsigned p = ptr[v];
            if (key64[p] <= key64[v]) {
                unsigned q = ptr[p];
                if (q != p) {
                    ptr[v] = q;
                    chg = 1u;
                }
            }
        }
        __syncthreads();
        unsigned fin = (chg == 0u);
        __syncthreads();
        if (t == 0) chg = 0u;
        __syncthreads();
        if (fin) break;
    }
    // ---- S: subtree sizes of ANSV forest by child-sum iteration ----
    unsigned* Sc = Sa;
    unsigned* Sn = Sb;
    for (int v = t; v < N; v += 1024) Sc[v] = 1u;
    __syncthreads();
    for (int round = 0; round < 64; ++round) {
        for (int v = t; v < N; v += 1024) Sn[v] = 1u;
        __syncthreads();
        for (int v = t; v < N; v += 1024)
            if (v != 0) atomicAdd(&Sn[ptr[v]], Sc[v]);
        __syncthreads();
        for (int v = t; v < N; v += 1024)
            if (Sn[v] != Sc[v]) chg = 1u;
        __syncthreads();
        unsigned fin = (chg == 0u);
        __syncthreads();
        if (t == 0) chg = 0u;
        __syncthreads();
        unsigned* tmp = Sc; Sc = Sn; Sn = tmp;
        if (fin) break;
    }
    // ---- r-major sort key: (r<<44)|(wbits<<12)|v ----
    for (int v = t; v < N; v += 1024) {
        order[v] = (v == 0)
                       ? (0xFFFFFull << 44)
                       : (((unsigned long long)ptr[v]) << 44) |
                             (((unsigned long long)keyw[v]) << 12) | (unsigned)v;
    }
    __syncthreads();
    for (unsigned k = 2; k <= 4096; k <<= 1) {
        for (unsigned j = k >> 1; j > 0; j >>= 1) {
            for (unsigned i = t; i < 4096; i += 1024) {
                unsigned p = i ^ j;
                if (p > i) {
                    unsigned long long a = order[i], b = order[p];
                    bool up = ((i & k) == 0);
                    if ((a > b) == up) {
                        order[i] = b;
                        order[p] = a;
                    }
                }
            }
            __syncthreads();
        }
    }
    // ---- segmented inclusive scan of S over sibling groups ----
    for (int i = t; i < 4096; i += 1024) {
        unsigned vv = (unsigned)order[i] & 0xFFFu;
        T[i] = Sc[vv];
    }
    __syncthreads();
    for (int d = 1; d < 4096; d <<= 1) {
        unsigned addv[4];
#pragma unroll
        for (int q = 0; q < 4; ++q) {
            int i = t + 1024 * q;
            addv[q] = 0;
            if (i >= d && (order[i] >> 44) == (order[i - d] >> 44)) addv[q] = T[i - d];
        }
        __syncthreads();
#pragma unroll
        for (int q = 0; q < 4; ++q) T[t + 1024 * q] += addv[q];
        __syncthreads();
    }
    for (int i = t; i < 4096; i += 1024) {
        unsigned vv = (unsigned)order[i] & 0xFFFu;
        if (vv) {
            vA[vv] = 1u + T[i] - Sc[vv];
            jA[vv] = ptr[vv];
        }
    }
    if (t == 0) {
        vA[0] = 0u;
        jA[0] = 0u;
    }
    __syncthreads();
    // ---- pointer-doubling: pos(v) = sum of vA along jA path ----
    {
        unsigned *va = vA, *vb = vB, *ja = jA, *jb = jB;
        for (int r = 0; r < 12; ++r) {
            for (int v = t; v < N; v += 1024) {
                unsigned j2 = ja[v];
                vb[v] = va[v] + va[j2];
                jb[v] = ja[j2];
            }
            __syncthreads();
            unsigned* tmp;
            tmp = va; va = vb; vb = tmp;
            tmp = ja; ja = jb; jb = tmp;
        }
        for (int v = t; v < N; v += 1024) {
            if (v) out[2 * (va[v] - 1) + 1] = __uint_as_float(keyw[v]);
        }
    }
}

// ---------------------------------------------------------------------------
extern "C" void kernel_launch(void* const* d_in, const int* in_sizes, int n_in,
                              void* d_out, int out_size, void* d_ws, size_t ws_size,
                              hipStream_t stream) {
    const float* x = (const float*)d_in[0];
    float* out = (float*)d_out;  // [N-1][2]: (birth=0, death)
    const size_t dbytes = (size_t)N * N * 4;

    if (ws_size >= dbytes + 81920) {
        // Cached-D path (R14 structure + round-0 fused into build_d).
        float* D = (float*)d_ws;
        unsigned char* st = (unsigned char*)d_ws + dbytes;
        unsigned long long* best = (unsigned long long*)st;            // 32 KB
        unsigned* comp = (unsigned*)(st + 32768);                      // 16 KB
        unsigned long long* edges = (unsigned long long*)(st + 49152); // 32760 B
        unsigned* nedges = (unsigned*)(st + 81912);
        unsigned* done = (unsigned*)(st + 81916);

        dim3 grid(N / 64, N / 64);
        init_kernel<<<16, 256, 0, stream>>>(comp, best, nedges, done);
        build_d_kernel<<<grid, 256, 0, stream>>>(x, D, best);  // emits round-0 best
        merge_kernel<<<1, 1024, 0, stream>>>(comp, best, edges, nedges, done);
        for (int r = 1; r < 12; ++r) {
            minedge_d_kernel<<<256, 256, 0, stream>>>(D, comp, best, done);
            merge_kernel<<<1, 1024, 0, stream>>>(comp, best, edges, nedges, done);
        }
        replay_kernel<<<1, 1024, 0, stream>>>(edges, nedges, out);
    } else {
        // Recompute fallback (R13-verified structure).
        unsigned char* ws = (unsigned char*)d_ws;
        unsigned* comp = (unsigned*)ws;                                  // 16 KB
        unsigned long long* best = (unsigned long long*)(ws + 16384);    // 32 KB
        unsigned long long* edges = (unsigned long long*)(ws + 49152);   // 32 KB
        unsigned* nedges = (unsigned*)(ws + 81920);
        unsigned* done = (unsigned*)(ws + 81984);

        init_kernel<<<16, 256, 0, stream>>>(comp, best, nedges, done);
        for (int r = 0; r < 12; ++r) {
            minedge_kernel<<<256, 256, 0, stream>>>(x, comp, best, done);
            merge_kernel<<<1, 1024, 0, stream>>>(comp, best, edges, nedges, done);
        }
        replay_kernel<<<1, 1024, 0, stream>>>(edges, nedges, out);
    }
}